// Round 17
// baseline (101.845 us; speedup 1.0000x reference)
//
#include <hip/hip_runtime.h>

typedef unsigned short u16;
typedef unsigned int u32;
typedef __attribute__((ext_vector_type(8))) short short8;
typedef __attribute__((ext_vector_type(4))) float f32x4;

__device__ __forceinline__ u16 f2b(float f) {
  u32 u = __builtin_bit_cast(u32, f);
  u32 r = (u + 0x7FFFu + ((u >> 16) & 1u)) >> 16;  // RNE f32->bf16
  return (u16)r;
}

__device__ __forceinline__ void gl_lds16(const void* g, void* l) {
  __builtin_amdgcn_global_load_lds(
      (const __attribute__((address_space(1))) u32*)g,
      (__attribute__((address_space(3))) u32*)l, 16, 0, 0);
}

struct Ptrs8 { const float* p[8]; };

// ---------------------------------------------------------------------------
// Fused pre-pass (ONE launch): blockIdx < 2048 -> wt_pack, else xh_pack.
//   wt_pack: Wt[g*1024+n][h*1024+k] = bf16(W[h*4+g][k][n])
//   xh_pack: Ap[m][k] = bf16(k<1024 ? x[m][k] : h0[m][k-1024])
// ---------------------------------------------------------------------------
__global__ __launch_bounds__(256) void prepack(Ptrs8 w,
                                               const float* __restrict__ x,
                                               const float* __restrict__ h0,
                                               u16* __restrict__ Wt,
                                               u16* __restrict__ Ap) {
  __shared__ float lds[64 * 64];     // 16 KB (wt branch only)
  const int tid = threadIdx.x;
  const int bid = blockIdx.x;

  if (bid < 2048) {                       // ---- wt_pack ----
    const int mat = bid >> 8;             // 0..7
    const int g = mat & 3, h = mat >> 2;
    const int tile = bid & 255;
    const int kt = tile >> 4, nt = tile & 15;
    const float* __restrict__ src = w.p[mat];
#pragma unroll
    for (int i = 0; i < 4; ++i) {
      int c = tid + i * 256;
      int k = c >> 4, n4 = (c & 15) * 4;
      gl_lds16(src + (size_t)(kt * 64 + k) * 1024 + nt * 64 + n4, &lds[c * 4]);
    }
    asm volatile("s_waitcnt vmcnt(0)");
    __syncthreads();
#pragma unroll
    for (int i = 0; i < 2; ++i) {
      int c = tid + i * 256;
      int n = c & 63, kb = (c >> 6) * 8;
      short8 v;
#pragma unroll
      for (int j = 0; j < 8; ++j) v[j] = (short)f2b(lds[(kb + j) * 64 + n]);
      size_t off = (size_t)(g * 1024 + nt * 64 + n) * 2048 + h * 1024 + kt * 64 + kb;
      *reinterpret_cast<short8*>(Wt + off) = v;
    }
  } else {                                // ---- xh_pack ----
    int t = (bid - 2048) * 256 + tid;
    int m = t >> 8, kc = t & 255;
    const float* src = (kc < 128) ? (x + (size_t)m * 1024 + kc * 8)
                                  : (h0 + (size_t)m * 1024 + (kc - 128) * 8);
    float4 a = *reinterpret_cast<const float4*>(src);
    float4 bb = *reinterpret_cast<const float4*>(src + 4);
    short8 v;
    v[0] = (short)f2b(a.x); v[1] = (short)f2b(a.y);
    v[2] = (short)f2b(a.z); v[3] = (short)f2b(a.w);
    v[4] = (short)f2b(bb.x); v[5] = (short)f2b(bb.y);
    v[6] = (short)f2b(bb.z); v[7] = (short)f2b(bb.w);
    *reinterpret_cast<short8*>(Ap + (size_t)m * 2048 + kc * 8) = v;
  }
}

// ---------------------------------------------------------------------------
// Fused LSTM GEMM — r9 champion schedule; stage-issue hoisted before the
// phase's ds_reads (DMA gets ~50-200 cyc more slack per phase; same buffer
// hazard guarantees as before, verified: staged half was last read before
// the previous tile's closing barrier).
// 512 thr / 8 waves (2M x 4N), block 256m x (64n x 4 gates), BK=64, 32 iters.
// ---------------------------------------------------------------------------
#define LD8(base, off) (*reinterpret_cast<const short8*>((base) + (off)))
#define MFMA_(a, b, c) __builtin_amdgcn_mfma_f32_16x16x32_bf16(a, b, c, 0, 0, 0)

#define READ_A(DST, BASE)                                   \
  _Pragma("unroll")                                         \
  for (int mi = 0; mi < 4; ++mi) {                          \
    DST[mi][0] = LD8(Ab, arow + (BASE + mi) * 1024 + c0k);  \
    DST[mi][1] = LD8(Ab, arow + (BASE + mi) * 1024 + c1k);  \
  }
#define READ_B(DST, GB)                                     \
  _Pragma("unroll")                                         \
  for (int g = 0; g < 2; ++g) {                             \
    DST[g][0] = LD8(Bb, bbase + (GB + g) * 4096 + c0k);     \
    DST[g][1] = LD8(Bb, bbase + (GB + g) * 4096 + c1k);     \
  }
#define MFMA_QUAD(AF, BF, MO, GO)                                              \
  __builtin_amdgcn_s_setprio(1);                                               \
  _Pragma("unroll")                                                            \
  for (int mi = 0; mi < 4; ++mi)                                               \
    _Pragma("unroll")                                                          \
    for (int g = 0; g < 2; ++g) {                                              \
      acc[MO + mi][GO + g] = MFMA_(AF[mi][0], BF[g][0], acc[MO + mi][GO + g]); \
      acc[MO + mi][GO + g] = MFMA_(AF[mi][1], BF[g][1], acc[MO + mi][GO + g]); \
    }                                                                          \
  __builtin_amdgcn_s_setprio(0);

__global__ __launch_bounds__(512, 2) void lstm_fused(
    const u16* __restrict__ Ap, const float* __restrict__ c0,
    const u16* __restrict__ Wt, Ptrs8 b,
    float* __restrict__ out) {
  __shared__ u16 As[2][256 * 64];   // 32 KB each
  __shared__ u16 Bs[2][256 * 64];   // 32 KB each

  const int tid = threadIdx.x;
  const int lane = tid & 63;
  const int wid = tid >> 6;
  const int wr = wid >> 2;          // M half
  const int wc = wid & 3;           // n-16 block
  const int fl = lane & 15;
  const int hi = lane >> 4;
  const int lo7 = fl & 7;

  const int bid0 = blockIdx.x;
  const int sbid = (bid0 & 7) * 32 + (bid0 >> 3);  // XCD swizzle (256%8==0)
  const int m0 = (sbid >> 4) * 256;
  const int n0 = (sbid & 15) * 64;

  // stage maps: 2048 16B-chunks per tile, 4/thread, linear LDS dest,
  // global source pre-swizzled: chunk cg = cL ^ (row & 7).
  // A chunk i: rows [i*64,(i+1)*64); half0={0,2}, half1={1,3}.
  // B LDS row = g*64 + wc*16 + u; chunk i = gate i; half0={0,1}, half1={2,3}.
  int aoff[4], boff[4];
#pragma unroll
  for (int i = 0; i < 4; ++i) {
    const int L = tid + i * 512;
    const int r = L >> 3, cL = L & 7;
    const int cg = cL ^ (r & 7);
    aoff[i] = (m0 + r) * 2048 + cg * 8;
    const int ge = r >> 6, wce = (r >> 4) & 3, ue = r & 15;
    boff[i] = (ge * 1024 + n0 + wce * 16 + ue) * 2048 + cg * 8;
  }

  auto stageA = [&](int buf, int t, int h) {  // half h: chunks {h, h+2}
    const int k0 = t * 64;
    gl_lds16(Ap + aoff[h] + k0, &As[buf][(tid + h * 512) * 8]);
    gl_lds16(Ap + aoff[h + 2] + k0, &As[buf][(tid + (h + 2) * 512) * 8]);
  };
  auto stageB = [&](int buf, int t, int h) {  // half h: chunks {2h, 2h+1}
    const int k0 = t * 64;
    gl_lds16(Wt + boff[2 * h] + k0, &Bs[buf][(tid + (2 * h) * 512) * 8]);
    gl_lds16(Wt + boff[2 * h + 1] + k0, &Bs[buf][(tid + (2 * h + 1) * 512) * 8]);
  };

  // fragment read bases (element offsets; lane-constant swizzle)
  const int c0k = (hi ^ lo7) * 8;          // ks=0 swizzled chunk
  const int c1k = ((4 + hi) ^ lo7) * 8;    // ks=1
  const int arow = (wr * 128 + fl) * 64;
  const int bbase = (wc * 16 + fl) * 64;   // + g*4096

  f32x4 acc[8][4] = {};   // [mi][gate]

  // prologue: tile 0 in steady-state issue order Bh0, Ah0, Ah1, Bh1
  stageB(0, 0, 0);
  stageA(0, 0, 0);
  stageA(0, 0, 1);
  stageB(0, 0, 1);

  for (int t = 0; t < 31; ++t) {
    const int cur = t & 1, nxt = cur ^ 1;
    const u16* Ab = &As[cur][0];
    const u16* Bb = &Bs[cur][0];
    short8 af03[4][2], af47[4][2], bf01[2][2], bf23[2][2];

    // P1: wait Bh0(t)+Ah0(t); stage Bh0(t+1) early; read af03,bf01
    asm volatile("s_waitcnt vmcnt(4)" ::: "memory");
    __builtin_amdgcn_s_barrier();
    stageB(nxt, t + 1, 0);
    READ_A(af03, 0)
    READ_B(bf01, 0)
    MFMA_QUAD(af03, bf01, 0, 0)

    // P2: wait Ah1(t); stage Ah0(t+1) early; read af47
    asm volatile("s_waitcnt vmcnt(4)" ::: "memory");
    __builtin_amdgcn_s_barrier();
    stageA(nxt, t + 1, 0);
    READ_A(af47, 4)
    MFMA_QUAD(af47, bf01, 4, 0)

    // P3: wait Bh1(t); stage Ah1(t+1) early; read bf23
    asm volatile("s_waitcnt vmcnt(4)" ::: "memory");
    __builtin_amdgcn_s_barrier();
    stageA(nxt, t + 1, 1);
    READ_B(bf23, 2)
    MFMA_QUAD(af03, bf23, 0, 2)

    // P4: no wait; stage Bh1(t+1)
    __builtin_amdgcn_s_barrier();
    stageB(nxt, t + 1, 1);
    MFMA_QUAD(af47, bf23, 4, 2)
  }

  // ---- t = 31 peeled (no stages; drain waits 4 -> 2 -> 0) ----
  {
    const u16* Ab = &As[1][0];
    const u16* Bb = &Bs[1][0];
    short8 af03[4][2], af47[4][2], bf01[2][2], bf23[2][2];

    asm volatile("s_waitcnt vmcnt(4)" ::: "memory");
    __builtin_amdgcn_s_barrier();
    READ_A(af03, 0)
    READ_B(bf01, 0)
    MFMA_QUAD(af03, bf01, 0, 0)

    asm volatile("s_waitcnt vmcnt(2)" ::: "memory");
    __builtin_amdgcn_s_barrier();
    READ_A(af47, 4)
    MFMA_QUAD(af47, bf01, 4, 0)

    asm volatile("s_waitcnt vmcnt(0)" ::: "memory");
    __builtin_amdgcn_s_barrier();
    READ_B(bf23, 2)
    MFMA_QUAD(af03, bf23, 0, 2)

    __builtin_amdgcn_s_barrier();
    MFMA_QUAD(af47, bf23, 4, 2)
  }

  // ---- fused epilogue: bias (from raw b_*) + gates + cell update ----
  const int col = n0 + wc * 16 + fl;
  float bv[4];
#pragma unroll
  for (int g = 0; g < 4; ++g) bv[g] = b.p[g][col] + b.p[4 + g][col];

#pragma unroll
  for (int mi = 0; mi < 8; ++mi) {
#pragma unroll
    for (int r = 0; r < 4; ++r) {
      const int row = m0 + wr * 128 + mi * 16 + hi * 4 + r;
      const float zi = acc[mi][0][r] + bv[0];
      const float zf = acc[mi][1][r] + bv[1];
      const float zg = acc[mi][2][r] + bv[2];
      const float zo = acc[mi][3][r] + bv[3];
      const float ig = 1.f / (1.f + __expf(-zi));
      const float fg = 1.f / (1.f + __expf(-zf));
      const float gg = 1.f - 2.f / (__expf(2.f * zg) + 1.f);  // tanh
      const float og = 1.f / (1.f + __expf(-zo));
      const float c0v = c0[(size_t)row * 1024 + col];
      const float c1 = fg * c0v + ig * gg;
      const float h1 = og * c1;
      out[(size_t)row * 1024 + col] = h1;
      out[(size_t)4194304 + (size_t)row * 1024 + col] = c1;
    }
  }
}

// ---------------------------------------------------------------------------
extern "C" void kernel_launch(void* const* d_in, const int* in_sizes, int n_in,
                              void* d_out, int out_size, void* d_ws, size_t ws_size,
                              hipStream_t stream) {
  const float* x  = (const float*)d_in[0];
  const float* h0 = (const float*)d_in[1];
  const float* c0 = (const float*)d_in[2];
  Ptrs8 w, b;
  for (int i = 0; i < 4; ++i) {
    w.p[i]     = (const float*)d_in[3 + 2 * i];
    b.p[i]     = (const float*)d_in[4 + 2 * i];
    w.p[4 + i] = (const float*)d_in[11 + 2 * i];
    b.p[4 + i] = (const float*)d_in[12 + 2 * i];
  }
  u16* Wt = (u16*)d_ws;                                        // 16 MB
  u16* Ap = (u16*)((char*)d_ws + (size_t)4096 * 2048 * 2);     // 16 MB
  float* out = (float*)d_out;

  prepack<<<6144, 256, 0, stream>>>(w, x, h0, Wt, Ap);
  lstm_fused<<<256, 512, 0, stream>>>(Ap, c0, Wt, b, out);
}

// Round 18
// 86.420 us; speedup vs baseline: 1.1785x; 1.1785x over previous
//
#include <hip/hip_runtime.h>

typedef unsigned short u16;
typedef unsigned int u32;
typedef __attribute__((ext_vector_type(8))) short short8;
typedef __attribute__((ext_vector_type(4))) float f32x4;

__device__ __forceinline__ u16 f2b(float f) {
  u32 u = __builtin_bit_cast(u32, f);
  u32 r = (u + 0x7FFFu + ((u >> 16) & 1u)) >> 16;  // RNE f32->bf16
  return (u16)r;
}

__device__ __forceinline__ void gl_lds16(const void* g, void* l) {
  __builtin_amdgcn_global_load_lds(
      (const __attribute__((address_space(1))) u32*)g,
      (__attribute__((address_space(3))) u32*)l, 16, 0, 0);
}

struct Ptrs8 { const float* p[8]; };

// ---------------------------------------------------------------------------
// Fused pre-pass (ONE launch): blockIdx < 2048 -> wt_pack, else xh_pack.
//   wt_pack: Wt[g*1024+n][h*1024+k] = bf16(W[h*4+g][k][n])
//   xh_pack: Ap[m][k] = bf16(k<1024 ? x[m][k] : h0[m][k-1024])
// ---------------------------------------------------------------------------
__global__ __launch_bounds__(256) void prepack(Ptrs8 w,
                                               const float* __restrict__ x,
                                               const float* __restrict__ h0,
                                               u16* __restrict__ Wt,
                                               u16* __restrict__ Ap) {
  __shared__ float lds[64 * 64];     // 16 KB (wt branch only)
  const int tid = threadIdx.x;
  const int bid = blockIdx.x;

  if (bid < 2048) {                       // ---- wt_pack ----
    const int mat = bid >> 8;             // 0..7
    const int g = mat & 3, h = mat >> 2;
    const int tile = bid & 255;
    const int kt = tile >> 4, nt = tile & 15;
    const float* __restrict__ src = w.p[mat];
#pragma unroll
    for (int i = 0; i < 4; ++i) {
      int c = tid + i * 256;
      int k = c >> 4, n4 = (c & 15) * 4;
      gl_lds16(src + (size_t)(kt * 64 + k) * 1024 + nt * 64 + n4, &lds[c * 4]);
    }
    asm volatile("s_waitcnt vmcnt(0)");
    __syncthreads();
#pragma unroll
    for (int i = 0; i < 2; ++i) {
      int c = tid + i * 256;
      int n = c & 63, kb = (c >> 6) * 8;
      short8 v;
#pragma unroll
      for (int j = 0; j < 8; ++j) v[j] = (short)f2b(lds[(kb + j) * 64 + n]);
      size_t off = (size_t)(g * 1024 + nt * 64 + n) * 2048 + h * 1024 + kt * 64 + kb;
      *reinterpret_cast<short8*>(Wt + off) = v;
    }
  } else {                                // ---- xh_pack ----
    int t = (bid - 2048) * 256 + tid;
    int m = t >> 8, kc = t & 255;
    const float* src = (kc < 128) ? (x + (size_t)m * 1024 + kc * 8)
                                  : (h0 + (size_t)m * 1024 + (kc - 128) * 8);
    float4 a = *reinterpret_cast<const float4*>(src);
    float4 bb = *reinterpret_cast<const float4*>(src + 4);
    short8 v;
    v[0] = (short)f2b(a.x); v[1] = (short)f2b(a.y);
    v[2] = (short)f2b(a.z); v[3] = (short)f2b(a.w);
    v[4] = (short)f2b(bb.x); v[5] = (short)f2b(bb.y);
    v[6] = (short)f2b(bb.z); v[7] = (short)f2b(bb.w);
    *reinterpret_cast<short8*>(Ap + (size_t)m * 2048 + kc * 8) = v;
  }
}

// ---------------------------------------------------------------------------
// Fused LSTM GEMM — r9 champion schedule (verbatim; stage AFTER reads — the
// r17 stage-early A/B showed DMA LDS-writes must land in the MFMA window,
// not the read window):
// 512 thr / 8 waves (2M x 4N), block 256m x (64n x 4 gates), BK=64, 32 iters.
// 4 phases/tile: [vmcnt wait -> barrier] -> quadrant ds_reads -> half-tile
// stage issue -> prio1 -> 16 MFMA -> prio0. Stage order Bh0,Ah0,Ah1,Bh1;
// steady-state waits all vmcnt(4). Wait->barrier->read ordering everywhere.
// Bias folded into the epilogue (raw b_* inputs).
// ---------------------------------------------------------------------------
#define LD8(base, off) (*reinterpret_cast<const short8*>((base) + (off)))
#define MFMA_(a, b, c) __builtin_amdgcn_mfma_f32_16x16x32_bf16(a, b, c, 0, 0, 0)

#define READ_A(DST, BASE)                                   \
  _Pragma("unroll")                                         \
  for (int mi = 0; mi < 4; ++mi) {                          \
    DST[mi][0] = LD8(Ab, arow + (BASE + mi) * 1024 + c0k);  \
    DST[mi][1] = LD8(Ab, arow + (BASE + mi) * 1024 + c1k);  \
  }
#define READ_B(DST, GB)                                     \
  _Pragma("unroll")                                         \
  for (int g = 0; g < 2; ++g) {                             \
    DST[g][0] = LD8(Bb, bbase + (GB + g) * 4096 + c0k);     \
    DST[g][1] = LD8(Bb, bbase + (GB + g) * 4096 + c1k);     \
  }
#define MFMA_QUAD(AF, BF, MO, GO)                                              \
  __builtin_amdgcn_s_setprio(1);                                               \
  _Pragma("unroll")                                                            \
  for (int mi = 0; mi < 4; ++mi)                                               \
    _Pragma("unroll")                                                          \
    for (int g = 0; g < 2; ++g) {                                              \
      acc[MO + mi][GO + g] = MFMA_(AF[mi][0], BF[g][0], acc[MO + mi][GO + g]); \
      acc[MO + mi][GO + g] = MFMA_(AF[mi][1], BF[g][1], acc[MO + mi][GO + g]); \
    }                                                                          \
  __builtin_amdgcn_s_setprio(0);

__global__ __launch_bounds__(512, 2) void lstm_fused(
    const u16* __restrict__ Ap, const float* __restrict__ c0,
    const u16* __restrict__ Wt, Ptrs8 b,
    float* __restrict__ out) {
  __shared__ u16 As[2][256 * 64];   // 32 KB each
  __shared__ u16 Bs[2][256 * 64];   // 32 KB each

  const int tid = threadIdx.x;
  const int lane = tid & 63;
  const int wid = tid >> 6;
  const int wr = wid >> 2;          // M half
  const int wc = wid & 3;           // n-16 block
  const int fl = lane & 15;
  const int hi = lane >> 4;
  const int lo7 = fl & 7;

  const int bid0 = blockIdx.x;
  const int sbid = (bid0 & 7) * 32 + (bid0 >> 3);  // XCD swizzle (256%8==0)
  const int m0 = (sbid >> 4) * 256;
  const int n0 = (sbid & 15) * 64;

  // stage maps: 2048 16B-chunks per tile, 4/thread, linear LDS dest,
  // global source pre-swizzled: chunk cg = cL ^ (row & 7).
  // A chunk i: rows [i*64,(i+1)*64); half0={0,2}, half1={1,3}.
  // B LDS row = g*64 + wc*16 + u; chunk i = gate i; half0={0,1}, half1={2,3}.
  int aoff[4], boff[4];
#pragma unroll
  for (int i = 0; i < 4; ++i) {
    const int L = tid + i * 512;
    const int r = L >> 3, cL = L & 7;
    const int cg = cL ^ (r & 7);
    aoff[i] = (m0 + r) * 2048 + cg * 8;
    const int ge = r >> 6, wce = (r >> 4) & 3, ue = r & 15;
    boff[i] = (ge * 1024 + n0 + wce * 16 + ue) * 2048 + cg * 8;
  }

  auto stageA = [&](int buf, int t, int h) {  // half h: chunks {h, h+2}
    const int k0 = t * 64;
    gl_lds16(Ap + aoff[h] + k0, &As[buf][(tid + h * 512) * 8]);
    gl_lds16(Ap + aoff[h + 2] + k0, &As[buf][(tid + (h + 2) * 512) * 8]);
  };
  auto stageB = [&](int buf, int t, int h) {  // half h: chunks {2h, 2h+1}
    const int k0 = t * 64;
    gl_lds16(Wt + boff[2 * h] + k0, &Bs[buf][(tid + (2 * h) * 512) * 8]);
    gl_lds16(Wt + boff[2 * h + 1] + k0, &Bs[buf][(tid + (2 * h + 1) * 512) * 8]);
  };

  // fragment read bases (element offsets; lane-constant swizzle)
  const int c0k = (hi ^ lo7) * 8;          // ks=0 swizzled chunk
  const int c1k = ((4 + hi) ^ lo7) * 8;    // ks=1
  const int arow = (wr * 128 + fl) * 64;
  const int bbase = (wc * 16 + fl) * 64;   // + g*4096

  f32x4 acc[8][4] = {};   // [mi][gate]

  // prologue: tile 0 in steady-state issue order Bh0, Ah0, Ah1, Bh1
  stageB(0, 0, 0);
  stageA(0, 0, 0);
  stageA(0, 0, 1);
  stageB(0, 0, 1);

  for (int t = 0; t < 31; ++t) {
    const int cur = t & 1, nxt = cur ^ 1;
    const u16* Ab = &As[cur][0];
    const u16* Bb = &Bs[cur][0];
    short8 af03[4][2], af47[4][2], bf01[2][2], bf23[2][2];

    // P1: wait Bh0(t)+Ah0(t); read af03,bf01; stage Bh0(t+1)
    asm volatile("s_waitcnt vmcnt(4)" ::: "memory");
    __builtin_amdgcn_s_barrier();
    READ_A(af03, 0)
    READ_B(bf01, 0)
    stageB(nxt, t + 1, 0);
    MFMA_QUAD(af03, bf01, 0, 0)

    // P2: wait Ah1(t); read af47; stage Ah0(t+1)
    asm volatile("s_waitcnt vmcnt(4)" ::: "memory");
    __builtin_amdgcn_s_barrier();
    READ_A(af47, 4)
    stageA(nxt, t + 1, 0);
    MFMA_QUAD(af47, bf01, 4, 0)

    // P3: wait Bh1(t); read bf23; stage Ah1(t+1)
    asm volatile("s_waitcnt vmcnt(4)" ::: "memory");
    __builtin_amdgcn_s_barrier();
    READ_B(bf23, 2)
    stageA(nxt, t + 1, 1);
    MFMA_QUAD(af03, bf23, 0, 2)

    // P4: no wait; stage Bh1(t+1)
    __builtin_amdgcn_s_barrier();
    stageB(nxt, t + 1, 1);
    MFMA_QUAD(af47, bf23, 4, 2)
  }

  // ---- t = 31 peeled (no stages; drain waits 4 -> 2 -> 0) ----
  {
    const u16* Ab = &As[1][0];
    const u16* Bb = &Bs[1][0];
    short8 af03[4][2], af47[4][2], bf01[2][2], bf23[2][2];

    asm volatile("s_waitcnt vmcnt(4)" ::: "memory");
    __builtin_amdgcn_s_barrier();
    READ_A(af03, 0)
    READ_B(bf01, 0)
    MFMA_QUAD(af03, bf01, 0, 0)

    asm volatile("s_waitcnt vmcnt(2)" ::: "memory");
    __builtin_amdgcn_s_barrier();
    READ_A(af47, 4)
    MFMA_QUAD(af47, bf01, 4, 0)

    asm volatile("s_waitcnt vmcnt(0)" ::: "memory");
    __builtin_amdgcn_s_barrier();
    READ_B(bf23, 2)
    MFMA_QUAD(af03, bf23, 0, 2)

    __builtin_amdgcn_s_barrier();
    MFMA_QUAD(af47, bf23, 4, 2)
  }

  // ---- fused epilogue: bias (from raw b_*) + gates + cell update ----
  const int col = n0 + wc * 16 + fl;
  float bv[4];
#pragma unroll
  for (int g = 0; g < 4; ++g) bv[g] = b.p[g][col] + b.p[4 + g][col];

#pragma unroll
  for (int mi = 0; mi < 8; ++mi) {
#pragma unroll
    for (int r = 0; r < 4; ++r) {
      const int row = m0 + wr * 128 + mi * 16 + hi * 4 + r;
      const float zi = acc[mi][0][r] + bv[0];
      const float zf = acc[mi][1][r] + bv[1];
      const float zg = acc[mi][2][r] + bv[2];
      const float zo = acc[mi][3][r] + bv[3];
      const float ig = 1.f / (1.f + __expf(-zi));
      const float fg = 1.f / (1.f + __expf(-zf));
      const float gg = 1.f - 2.f / (__expf(2.f * zg) + 1.f);  // tanh
      const float og = 1.f / (1.f + __expf(-zo));
      const float c0v = c0[(size_t)row * 1024 + col];
      const float c1 = fg * c0v + ig * gg;
      const float h1 = og * c1;
      out[(size_t)row * 1024 + col] = h1;
      out[(size_t)4194304 + (size_t)row * 1024 + col] = c1;
    }
  }
}

// ---------------------------------------------------------------------------
extern "C" void kernel_launch(void* const* d_in, const int* in_sizes, int n_in,
                              void* d_out, int out_size, void* d_ws, size_t ws_size,
                              hipStream_t stream) {
  const float* x  = (const float*)d_in[0];
  const float* h0 = (const float*)d_in[1];
  const float* c0 = (const float*)d_in[2];
  Ptrs8 w, b;
  for (int i = 0; i < 4; ++i) {
    w.p[i]     = (const float*)d_in[3 + 2 * i];
    b.p[i]     = (const float*)d_in[4 + 2 * i];
    w.p[4 + i] = (const float*)d_in[11 + 2 * i];
    b.p[4 + i] = (const float*)d_in[12 + 2 * i];
  }
  u16* Wt = (u16*)d_ws;                                        // 16 MB
  u16* Ap = (u16*)((char*)d_ws + (size_t)4096 * 2048 * 2);     // 16 MB
  float* out = (float*)d_out;

  prepack<<<6144, 256, 0, stream>>>(w, x, h0, Wt, Ap);
  lstm_fused<<<256, 512, 0, stream>>>(Ap, c0, Wt, b, out);
}